// Round 5
// baseline (596.143 us; speedup 1.0000x reference)
//
#include <hip/hip_runtime.h>

// ---------------------------------------------------------------------------
// O3onO2 tensor product, LS=[0,1,2,3], MULS=64 each, N=65536, DIM=1024.
// out = x @ M^T, M block-diagonal per m-group: 256x256, 384x384, 256x256,
// 128x128 (bf16). K-order in group m: block L (L>=m), si in {0,1}, i in
// [0,64): K = (L-m)*128 + si*64 + i (m>0), K = L*64 + i (m=0); the x column
// feeding K is x[:, 64L^2 + i*(2L+1) + j], j = (si==0 ? L+m : L-m).
//
// R1: LDS-staged coalesced epilogue. 204 us.   R2/R3/R4: regressions
// (B-amortization loss / reg spills / no-MLP burst), reverted.
// R5: two-kernel split. permute_x streams x -> xg (bf16, per-group K-major,
//     a pure within-row column permutation; 128 MB in ws, L3-resident).
//     tp_gemm then has NO x staging and NO barriers before the epilogue:
//     A-frags are contiguous bhalf8 global loads from xg, B-frags from
//     L2-resident M. Falls back to the R1 kernel if ws is too small.
// ---------------------------------------------------------------------------

typedef __attribute__((ext_vector_type(8))) short bhalf8_t;   // 8 x bf16 bits
typedef __attribute__((ext_vector_type(4))) float f32x4_t;

#define NROWS 65536
#define DIMV  1024

// M_m element offsets in workspace (bf16 elements)
#define M0_OFF 0
#define M1_OFF 65536
#define M2_OFF 212992
#define M3_OFF 278528
#define M_TOTAL 294912

// xg: starts at 1 MB into ws (shorts): segments per m-group, K_m=256/384/256/128
#define XG_SH_OFF 524288
#define SEG0 0
#define SEG1 16777216
#define SEG2 41943040
#define SEG3 58720256
#define WS_NEED 135266304ull   // 1 MB + 128 MB

// Epilogue LDS tile: 16 rows x 1024 cols fp32, padded row stride.
#define OP 1028

__device__ __forceinline__ short f2bf(float f) {
    unsigned u = __builtin_bit_cast(unsigned, f);
    u = (u + 0x7FFFu + ((u >> 16) & 1u)) >> 16;   // round-to-nearest-even
    return (short)u;
}

// ---------------------------------------------------------------------------
// Kernel 1: build block-diagonal group matrices M_m (bf16) into workspace.
// ---------------------------------------------------------------------------
__global__ __launch_bounds__(256) void build_M(const float* __restrict__ w,
                                               const float* __restrict__ hz,
                                               const float* __restrict__ hp,
                                               const float* __restrict__ hn,
                                               short* __restrict__ M) {
    int idx = blockIdx.x * 256 + threadIdx.x;
    if (idx >= M_TOTAL) return;

    int m, A, B;
    if (idx < M1_OFF)      { m = 0; int lo = idx;            A = lo / 256u; B = lo - A * 256; }
    else if (idx < M2_OFF) { m = 1; int lo = idx - M1_OFF;   A = lo / 384u; B = lo - A * 384; }
    else if (idx < M3_OFF) { m = 2; int lo = idx - M2_OFF;   A = lo / 256u; B = lo - A * 256; }
    else                   { m = 3; int lo = idx - M3_OFF;   A = lo / 128u; B = lo - A * 128; }

    int ob, so, o, ib, si, i;
    if (m == 0) { ob = A >> 6;       so = 0;            o = A & 63;
                  ib = B >> 6;       si = 0;            i = B & 63; }
    else        { ob = (A >> 7) + m; so = (A >> 6) & 1; o = A & 63;
                  ib = (B >> 7) + m; si = (B >> 6) & 1; i = B & 63; }

    int p = ob * 4 + ib;
    float wv = w[p * 4096 + o * 64 + i];
    float coef;
    if (m == 0) {
        coef = hz[p];
    } else {
        float hpv = hp[p * 3 + (m - 1)];
        float hnv = hn[p * 3 + (m - 1)];
        coef = (so == 0) ? ((si == 0) ? hpv : hnv)
                         : ((si == 0) ? -hnv : hpv);
    }
    M[idx] = f2bf(wv * coef);
}

// ---------------------------------------------------------------------------
// Kernel A: x (fp32, [n][1024]) -> xg (bf16, per-group K-major [n][K_m]).
// Pure within-row column permutation + cast. 256 thr, 16 rows/WG, 32 KB LDS.
// ---------------------------------------------------------------------------
__global__ __launch_bounds__(256) void permute_x(const float* __restrict__ x,
                                                 short* __restrict__ xg) {
    __shared__ __align__(16) short lbuf[16 * 1024];
    const int t = threadIdx.x;
    const int rowbase = blockIdx.x << 4;

    // load 16 rows coalesced, cast, store linear bf16 rows in LDS
#pragma unroll
    for (int p = 0; p < 16; ++p) {
        const int id  = p * 256 + t;
        const int row = id >> 8;
        const int c4  = id & 255;
        const float4 v = *(const float4*)(x + (size_t)(rowbase + row) * DIMV + c4 * 4);
        short* d = &lbuf[row * 1024 + c4 * 4];
        d[0] = f2bf(v.x); d[1] = f2bf(v.y); d[2] = f2bf(v.z); d[3] = f2bf(v.w);
    }
    __syncthreads();

    // emit 16 rows x 128 bhalf8 chunks, each a strided 8-gather from its row
#pragma unroll
    for (int p = 0; p < 8; ++p) {
        const int cid = p * 256 + t;
        const int row = cid >> 7;
        const int kc  = cid & 127;
        int m, klocal, Km; size_t seg;
        if (kc < 32)       { m = 0; klocal = kc << 3;         Km = 256; seg = SEG0; }
        else if (kc < 80)  { m = 1; klocal = (kc - 32) << 3;  Km = 384; seg = SEG1; }
        else if (kc < 112) { m = 2; klocal = (kc - 80) << 3;  Km = 256; seg = SEG2; }
        else               { m = 3; klocal = (kc - 112) << 3; Km = 128; seg = SEG3; }
        int L, si, i0;
        if (m == 0) { L = klocal >> 6;       si = 0;                 i0 = klocal & 63; }
        else        { L = (klocal >> 7) + m; si = (klocal >> 6) & 1; i0 = klocal & 63; }
        const int j    = (si == 0) ? (L + m) : (L - m);
        const int st   = 2 * L + 1;
        const int base = 64 * L * L + j + i0 * st;
        const short* s = &lbuf[row * 1024];
        bhalf8_t vv;
#pragma unroll
        for (int k = 0; k < 8; ++k) vv[k] = s[base + k * st];
        *(bhalf8_t*)&xg[seg + (size_t)(rowbase + row) * Km + klocal] = vv;
    }
}

// ---------------------------------------------------------------------------
// Kernel B: barrier-free GEMM. One WG = 64 rows x all 1024 out cols, 1024
// threads (16 waves). Waves 0-3: m=0, 4-9: m=1, 10-13: m=2, 14-15: m=3.
// A-frags: contiguous bhalf8 from xg. B-frags: L2-resident M. Epilogue:
// LDS un-permute + coalesced float4 stores (R1).
// ---------------------------------------------------------------------------
__global__ __launch_bounds__(1024) void tp_gemm(const short* __restrict__ xg,
                                                const short* __restrict__ Mall,
                                                float* __restrict__ out) {
    __shared__ __align__(16) float obuf[16 * OP];

    const int tid  = threadIdx.x;
    const int lane = tid & 63;
    const int lr   = lane & 15;
    const int q    = lane >> 4;
    const int wv   = tid >> 6;
    const int rowbase = blockIdx.x << 6;

    int m, cb;
    if (wv < 4)       { m = 0; cb = wv << 6; }
    else if (wv < 10) { m = 1; cb = (wv - 4) << 6; }
    else if (wv < 14) { m = 2; cb = (wv - 10) << 6; }
    else              { m = 3; cb = (wv - 14) << 6; }
    const int Wm   = (m == 1) ? 384 : ((m == 3) ? 128 : 256);
    const int Moff = (m == 0) ? M0_OFF : (m == 1) ? M1_OFF : (m == 2) ? M2_OFF : M3_OFF;
    const size_t xseg = (m == 0) ? SEG0 : (m == 1) ? SEG1 : (m == 2) ? SEG2 : SEG3;
    const short* __restrict__ Mg  = Mall + Moff;
    const short* __restrict__ xgm = xg + xseg;

    // hoisted row-base pointers
    const short* pa[4]; const short* pb[4];
#pragma unroll
    for (int r = 0; r < 4; ++r)
        pa[r] = xgm + (size_t)(rowbase + r * 16 + lr) * Wm + q * 8;
#pragma unroll
    for (int c = 0; c < 4; ++c)
        pb[c] = Mg + (size_t)(cb + c * 16 + lr) * Wm + q * 8;

    f32x4_t acc[4][4];   // [col-tile][row-tile] -> 64 AGPRs
#pragma unroll
    for (int c = 0; c < 4; ++c)
#pragma unroll
        for (int r = 0; r < 4; ++r)
            acc[c][r] = (f32x4_t){0.f, 0.f, 0.f, 0.f};

    const int nkc = Wm >> 5;   // 8 / 12 / 8 / 4 K-chunks of 32
#pragma unroll 2
    for (int kc = 0; kc < nkc; ++kc) {
        const int ko = kc * 32;
        bhalf8_t a[4];
#pragma unroll
        for (int r = 0; r < 4; ++r)
            a[r] = *(const bhalf8_t*)(pa[r] + ko);
#pragma unroll
        for (int c = 0; c < 4; ++c) {
            const bhalf8_t b = *(const bhalf8_t*)(pb[c] + ko);
#pragma unroll
            for (int r = 0; r < 4; ++r)
                acc[c][r] = __builtin_amdgcn_mfma_f32_16x16x32_bf16(
                    a[r], b, acc[c][r], 0, 0, 0);
        }
    }

    // ---- epilogue: un-permute columns via LDS, drain with coalesced float4.
    // C/D layout: col = lane&15, row = (lane>>4)*4 + reg   [m89-verified]
    int origc[4];
#pragma unroll
    for (int c = 0; c < 4; ++c) {
        const int P = cb + c * 16 + lr;
        int ob, o, jo;
        if (m == 0) { ob = P >> 6;       o = P & 63; jo = ob; }
        else        { ob = (P >> 7) + m; o = P & 63;
                      jo = ob + ((((P >> 6) & 1) == 0) ? m : -m); }
        origc[c] = 64 * ob * ob + o * (2 * ob + 1) + jo;
    }

#pragma unroll
    for (int r = 0; r < 4; ++r) {
        if (r) __syncthreads();          // prev drain done before overwrite
#pragma unroll
        for (int c = 0; c < 4; ++c) {
#pragma unroll
            for (int g = 0; g < 4; ++g)
                obuf[(q * 4 + g) * OP + origc[c]] = acc[c][r][g];
        }
        __syncthreads();
#pragma unroll
        for (int it = 0; it < 4; ++it) {
            const int jj  = it * 1024 + tid;
            const int row = jj >> 8;
            const int c4  = (jj & 255) << 2;
            const float4 v = *(const float4*)&obuf[row * OP + c4];
            *(float4*)&out[(size_t)(rowbase + r * 16 + row) * DIMV + c4] = v;
        }
    }
}

// ---------------------------------------------------------------------------
// Fallback (R1, 204 us): used when ws can't hold xg.
// ---------------------------------------------------------------------------
template<int L>
__device__ __forceinline__ void stage_block_fb(const float* __restrict__ x, int rowbase,
                                               short* __restrict__ xb, int tid) {
    constexpr int nch = 2 * L + 1;
    constexpr int d4  = 16 * nch;
    constexpr int RS  = nch * 72;
    constexpr int bo  = 64 * L * L;
#pragma unroll
    for (int e = 0; e < nch; ++e) {
        int id  = e * 1024 + tid;
        int row = id / d4;
        int cc  = id - row * d4;
        int col = cc * 4;
        const float4 v = *(const float4*)(x + (size_t)(rowbase + row) * DIMV + bo + col);
        short* dst = &xb[row * RS];
        { int ci = col;     int i = ci / nch; int ji = ci - i * nch; dst[ji * 72 + i] = f2bf(v.x); }
        { int ci = col + 1; int i = ci / nch; int ji = ci - i * nch; dst[ji * 72 + i] = f2bf(v.y); }
        { int ci = col + 2; int i = ci / nch; int ji = ci - i * nch; dst[ji * 72 + i] = f2bf(v.z); }
        { int ci = col + 3; int i = ci / nch; int ji = ci - i * nch; dst[ji * 72 + i] = f2bf(v.w); }
    }
}

template<int L>
__device__ __forceinline__ void compute_block_fb(const short* __restrict__ xb,
                                                 const short* __restrict__ Mg,
                                                 int m, int Wm, int cb, int lr, int q,
                                                 f32x4_t (&acc)[4][4]) {
    if (m > L) return;
    constexpr int nch = 2 * L + 1;
    constexpr int RS  = nch * 72;
    const int nsi = (m == 0) ? 1 : 2;
    for (int si = 0; si < nsi; ++si) {
        const int ji    = L + ((si == 0) ? m : -m);
        const int kbase = (m == 0) ? (L << 6) : (((L - m) << 7) + (si << 6));
#pragma unroll
        for (int kk = 0; kk < 2; ++kk) {
            bhalf8_t a[4];
            const int eo = ji * 72 + kk * 32 + q * 8;
#pragma unroll
            for (int r = 0; r < 4; ++r)
                a[r] = *(const bhalf8_t*)&xb[(r * 16 + lr) * RS + eo];
            const int ko = kbase + kk * 32 + q * 8;
#pragma unroll
            for (int c = 0; c < 4; ++c) {
                const bhalf8_t b = *(const bhalf8_t*)&Mg[(cb + c * 16 + lr) * Wm + ko];
#pragma unroll
                for (int r = 0; r < 4; ++r)
                    acc[c][r] = __builtin_amdgcn_mfma_f32_16x16x32_bf16(
                        a[r], b, acc[c][r], 0, 0, 0);
            }
        }
    }
}

__global__ __launch_bounds__(1024) void tp_main_fb(const float* __restrict__ x,
                                                   const short* __restrict__ Mall,
                                                   float* __restrict__ out) {
    __shared__ __align__(16) char smem[16 * OP * 4];
    short* __restrict__ xbuf = (short*)smem;
    float* __restrict__ obuf = (float*)smem;

    const int tid  = threadIdx.x;
    const int lane = tid & 63;
    const int lr   = lane & 15;
    const int q    = lane >> 4;
    const int wv   = tid >> 6;
    const int rowbase = blockIdx.x << 6;

    int m, cb;
    if (wv < 4)       { m = 0; cb = wv << 6; }
    else if (wv < 10) { m = 1; cb = (wv - 4) << 6; }
    else if (wv < 14) { m = 2; cb = (wv - 10) << 6; }
    else              { m = 3; cb = (wv - 14) << 6; }
    const int Wm   = (m == 1) ? 384 : ((m == 3) ? 128 : 256);
    const int Moff = (m == 0) ? M0_OFF : (m == 1) ? M1_OFF : (m == 2) ? M2_OFF : M3_OFF;
    const short* __restrict__ Mg = Mall + Moff;

    f32x4_t acc[4][4];
#pragma unroll
    for (int c = 0; c < 4; ++c)
#pragma unroll
        for (int r = 0; r < 4; ++r)
            acc[c][r] = (f32x4_t){0.f, 0.f, 0.f, 0.f};

    __syncthreads();
    stage_block_fb<0>(x, rowbase, xbuf, tid);
    __syncthreads();
    compute_block_fb<0>(xbuf, Mg, m, Wm, cb, lr, q, acc);
    __syncthreads();
    stage_block_fb<1>(x, rowbase, xbuf, tid);
    __syncthreads();
    compute_block_fb<1>(xbuf, Mg, m, Wm, cb, lr, q, acc);
    __syncthreads();
    stage_block_fb<2>(x, rowbase, xbuf, tid);
    __syncthreads();
    compute_block_fb<2>(xbuf, Mg, m, Wm, cb, lr, q, acc);
    __syncthreads();
    stage_block_fb<3>(x, rowbase, xbuf, tid);
    __syncthreads();
    compute_block_fb<3>(xbuf, Mg, m, Wm, cb, lr, q, acc);

    int origc[4];
#pragma unroll
    for (int c = 0; c < 4; ++c) {
        const int P = cb + c * 16 + lr;
        int ob, o, jo;
        if (m == 0) { ob = P >> 6;       o = P & 63; jo = ob; }
        else        { ob = (P >> 7) + m; o = P & 63;
                      jo = ob + ((((P >> 6) & 1) == 0) ? m : -m); }
        origc[c] = 64 * ob * ob + o * (2 * ob + 1) + jo;
    }

#pragma unroll
    for (int r = 0; r < 4; ++r) {
        __syncthreads();
#pragma unroll
        for (int c = 0; c < 4; ++c) {
#pragma unroll
            for (int g = 0; g < 4; ++g)
                obuf[(q * 4 + g) * OP + origc[c]] = acc[c][r][g];
        }
        __syncthreads();
#pragma unroll
        for (int it = 0; it < 4; ++it) {
            const int jj  = it * 1024 + tid;
            const int row = jj >> 8;
            const int c4  = (jj & 255) << 2;
            const float4 v = *(const float4*)&obuf[row * OP + c4];
            *(float4*)&out[(size_t)(rowbase + r * 16 + row) * DIMV + c4] = v;
        }
    }
}

// ---------------------------------------------------------------------------
extern "C" void kernel_launch(void* const* d_in, const int* in_sizes, int n_in,
                              void* d_out, int out_size, void* d_ws, size_t ws_size,
                              hipStream_t stream) {
    const float* x   = (const float*)d_in[0];
    const float* wts = (const float*)d_in[1];
    const float* hz  = (const float*)d_in[2];
    const float* hp  = (const float*)d_in[3];
    const float* hn  = (const float*)d_in[4];
    float* out = (float*)d_out;
    short* M   = (short*)d_ws;             // 589824 B
    short* xg  = (short*)d_ws + XG_SH_OFF; // 128 MB @ +1 MB

    build_M<<<dim3(M_TOTAL / 256), dim3(256), 0, stream>>>(wts, hz, hp, hn, M);
    if (ws_size >= WS_NEED) {
        permute_x<<<dim3(NROWS / 16), dim3(256), 0, stream>>>(x, xg);
        tp_gemm<<<dim3(NROWS / 64), dim3(1024), 0, stream>>>(xg, M, out);
    } else {
        tp_main_fb<<<dim3(NROWS / 64), dim3(1024), 0, stream>>>(x, M, out);
    }
}